// Round 3
// baseline (509.915 us; speedup 1.0000x reference)
//
#include <hip/hip_runtime.h>
#include <math.h>

#define NBATCH 64
#define Q      1000
#define C      1203
#define QC     1203000      // Q*C
#define QC4    300750       // QC/4
#define K      100
#define NBINS  2048         // fallback histogram bins (top 11 bits of mono key)
#define NSUB   32           // blocks per batch in pass1
#define SLICE  64           // candidate slots per pass1 block
#define CAP    (NSUB*SLICE) // 2048 candidates max per batch
#define BS     256
#define U      4            // float4 loads in flight per thread
#define TLOGIT 3.4f         // collect threshold: exp ~405 hits/batch for N(0,1), 15sigma above K

// monotonic uint key: key increasing <=> float increasing; ties broken by lower index
__device__ __forceinline__ unsigned int mono_key(float x) {
    unsigned int u = __float_as_uint(x);
    return u ^ ((u >> 31) ? 0xFFFFFFFFu : 0x80000000u);
}
__device__ __forceinline__ float key_to_float(unsigned int k) {
    unsigned int u = (k & 0x80000000u) ? (k ^ 0x80000000u) : ~k;
    return __uint_as_float(u);
}

// Pass 1: single full read of logits. Each block owns a slice of one batch,
// collects values >= TLOGIT into LDS (rare), writes its slice + count.
// No global atomics, no pre-zeroed state needed.
__global__ void __launch_bounds__(BS) pass1_kernel(const float* __restrict__ logits,
                                                   unsigned int* __restrict__ cnts,
                                                   uint2* __restrict__ cand) {
    __shared__ unsigned int lcnt;
    __shared__ uint2 lbuf[SLICE];
    int b   = blockIdx.x / NSUB;
    int sub = blockIdx.x % NSUB;
    if (threadIdx.x == 0) lcnt = 0u;
    __syncthreads();
    const float4* src = (const float4*)(logits + (size_t)b * QC);
    for (int base = 0; base < QC4; base += NSUB * BS * U) {
        int i0 = base + sub * (BS * U) + threadIdx.x;
        float4 v[U];
        #pragma unroll
        for (int u = 0; u < U; ++u) {
            int idx = i0 + u * BS;
            v[u] = (idx < QC4) ? src[idx] : make_float4(-1e30f, -1e30f, -1e30f, -1e30f);
        }
        float m = fmaxf(fmaxf(v[0].x, v[0].y), fmaxf(v[0].z, v[0].w));
        #pragma unroll
        for (int u = 1; u < U; ++u)
            m = fmaxf(m, fmaxf(fmaxf(v[u].x, v[u].y), fmaxf(v[u].z, v[u].w)));
        if (__any(m >= TLOGIT)) {
            #pragma unroll
            for (int u = 0; u < U; ++u) {
                int idx = i0 + u * BS;
                unsigned int e = 4u * (unsigned int)idx;
                if (v[u].x >= TLOGIT) { unsigned int s = atomicAdd(&lcnt, 1u); if (s < SLICE) lbuf[s] = make_uint2(mono_key(v[u].x), e + 0u); }
                if (v[u].y >= TLOGIT) { unsigned int s = atomicAdd(&lcnt, 1u); if (s < SLICE) lbuf[s] = make_uint2(mono_key(v[u].y), e + 1u); }
                if (v[u].z >= TLOGIT) { unsigned int s = atomicAdd(&lcnt, 1u); if (s < SLICE) lbuf[s] = make_uint2(mono_key(v[u].z), e + 2u); }
                if (v[u].w >= TLOGIT) { unsigned int s = atomicAdd(&lcnt, 1u); if (s < SLICE) lbuf[s] = make_uint2(mono_key(v[u].w), e + 3u); }
            }
        }
    }
    __syncthreads();
    unsigned int n = lcnt;
    uint2* slice = cand + ((size_t)b * NSUB + sub) * SLICE;
    unsigned int nw = n < SLICE ? n : SLICE;
    for (unsigned int i = threadIdx.x; i < nw; i += BS) slice[i] = lbuf[i];
    if (threadIdx.x == 0) cnts[b * NSUB + sub] = n;   // raw count; > SLICE marks overflow
}

// Finish: one block per batch. Validate fast path; gather candidates; if the
// fast path failed (too few hits / slice overflow) run an exact in-block
// histogram fallback over the batch. Then exact rank (key desc, idx asc) and
// write scores/labels/boxes.
__global__ void __launch_bounds__(BS) finish_kernel(const unsigned int* __restrict__ cnts,
                                                    const uint2* __restrict__ cand,
                                                    const float* __restrict__ logits,
                                                    const float* __restrict__ bbox,
                                                    const float* __restrict__ tsizes,
                                                    float* __restrict__ out) {
    __shared__ uint2 sc[CAP];
    __shared__ unsigned int lh[NBINS];
    __shared__ unsigned int soff[NSUB + 1];
    __shared__ unsigned int sn;
    int b = blockIdx.x;

    if (threadIdx.x == 0) {
        unsigned int off = 0;
        bool valid = true;
        for (int s = 0; s < NSUB; ++s) {
            unsigned int c = cnts[b * NSUB + s];
            soff[s] = off;
            if (c > SLICE) valid = false;
            off += (c > SLICE ? SLICE : c);
        }
        soff[NSUB] = off;
        sn = (valid && off >= (unsigned int)K) ? off : 0xFFFFFFFFu;
    }
    __syncthreads();
    unsigned int n = sn;

    if (n != 0xFFFFFFFFu) {
        // fast path: gather slices into LDS
        for (int s = 0; s < NSUB; ++s) {
            unsigned int o = soff[s];
            unsigned int c = soff[s + 1] - o;
            const uint2* slice = cand + ((size_t)b * NSUB + s) * SLICE;
            for (unsigned int i = threadIdx.x; i < c; i += BS) sc[o + i] = slice[i];
        }
        __syncthreads();
    } else {
        // exact fallback (fires only if TLOGIT assumption breaks for this batch)
        for (int i = threadIdx.x; i < NBINS; i += BS) lh[i] = 0u;
        __syncthreads();
        const float4* src = (const float4*)(logits + (size_t)b * QC);
        for (int i = threadIdx.x; i < QC4; i += BS) {
            float4 v = src[i];
            atomicAdd(&lh[mono_key(v.x) >> 21], 1u);
            atomicAdd(&lh[mono_key(v.y) >> 21], 1u);
            atomicAdd(&lh[mono_key(v.z) >> 21], 1u);
            atomicAdd(&lh[mono_key(v.w) >> 21], 1u);
        }
        __syncthreads();
        if (threadIdx.x == 0) {
            unsigned int cum = 0; int tb = 0;
            for (int i = NBINS - 1; i >= 0; --i) { cum += lh[i]; if (cum >= (unsigned int)K) { tb = i; break; } }
            lh[0] = ((unsigned int)tb) << 21;   // broadcast threshold (hist dead now)
            sn = 0u;
        }
        __syncthreads();
        unsigned int tk = lh[0];
        for (int i = threadIdx.x; i < QC4; i += BS) {
            float4 v = src[i];
            unsigned int e = 4u * (unsigned int)i;
            unsigned int k0 = mono_key(v.x), k1 = mono_key(v.y), k2 = mono_key(v.z), k3 = mono_key(v.w);
            if (k0 >= tk) { unsigned int s = atomicAdd(&sn, 1u); if (s < CAP) sc[s] = make_uint2(k0, e + 0u); }
            if (k1 >= tk) { unsigned int s = atomicAdd(&sn, 1u); if (s < CAP) sc[s] = make_uint2(k1, e + 1u); }
            if (k2 >= tk) { unsigned int s = atomicAdd(&sn, 1u); if (s < CAP) sc[s] = make_uint2(k2, e + 2u); }
            if (k3 >= tk) { unsigned int s = atomicAdd(&sn, 1u); if (s < CAP) sc[s] = make_uint2(k3, e + 3u); }
        }
        __syncthreads();
        n = sn < (unsigned int)CAP ? sn : (unsigned int)CAP;
    }

    float img_h = tsizes[2 * b + 0];
    float img_w = tsizes[2 * b + 1];
    float* scores = out;
    float* labels = out + NBATCH * K;
    float* boxes  = out + 2 * NBATCH * K;
    for (unsigned int i = threadIdx.x; i < n; i += BS) {
        uint2 me = sc[i];
        int rank = 0;
        for (unsigned int j = 0; j < n; ++j) {
            uint2 o = sc[j];
            if (o.x > me.x || (o.x == me.x && o.y < me.y)) rank++;
        }
        if (rank < K) {
            float v = key_to_float(me.x);
            double sd = 1.0 / (1.0 + exp(-(double)v));
            scores[b * K + rank] = (float)sd;
            unsigned int idx = me.y;
            unsigned int q   = idx / C;
            unsigned int lab = idx - q * C;
            labels[b * K + rank] = (float)lab;
            const float* bb = bbox + ((size_t)b * Q + q) * 4;
            float cx = bb[0], cy = bb[1], w = bb[2], h = bb[3];
            float* o = boxes + ((size_t)b * K + (size_t)rank) * 4;
            o[0] = (cx - 0.5f * w) * img_w;
            o[1] = (cy - 0.5f * h) * img_h;
            o[2] = (cx + 0.5f * w) * img_w;
            o[3] = (cy + 0.5f * h) * img_h;
        }
    }
}

extern "C" void kernel_launch(void* const* d_in, const int* in_sizes, int n_in,
                              void* d_out, int out_size, void* d_ws, size_t ws_size,
                              hipStream_t stream) {
    const float* logits = (const float*)d_in[0];   // 64*1000*1203 f32
    const float* bbox   = (const float*)d_in[1];   // 64*1000*4 f32
    const float* tsizes = (const float*)d_in[2];   // 64*2 f32
    float* out = (float*)d_out;                    // [scores 6400 | labels 6400 | boxes 25600]

    char* ws = (char*)d_ws;
    unsigned int* cnts = (unsigned int*)(ws);                  // 64*32*4 = 8 KiB
    uint2*        cand = (uint2*)(ws + 8192);                  // 64*32*64*8 = 1 MiB

    pass1_kernel<<<NBATCH * NSUB, BS, 0, stream>>>(logits, cnts, cand);
    finish_kernel<<<NBATCH, BS, 0, stream>>>(cnts, cand, logits, bbox, tsizes, out);
}